// Round 12
// baseline (305.835 us; speedup 1.0000x reference)
//
#include <hip/hip_runtime.h>
#include <stdint.h>

typedef float f4_t __attribute__((ext_vector_type(4)));
typedef float f16_t __attribute__((ext_vector_type(16)));
typedef __bf16 bf8_t __attribute__((ext_vector_type(8)));
typedef unsigned short us4_t __attribute__((ext_vector_type(4)));
typedef unsigned short us8_t __attribute__((ext_vector_type(8)));

static __device__ __forceinline__ unsigned short fbf(float f) {
    __bf16 b = (__bf16)f;
    return *(unsigned short*)&b;
}
static __device__ __forceinline__ float bf2f(unsigned short u) {
    union { uint32_t u; float f; } v; v.u = ((uint32_t)u) << 16;
    return v.f;
}
static __device__ __forceinline__ f4_t mfma16(bf8_t a, bf8_t b, f4_t c) {
    return __builtin_amdgcn_mfma_f32_16x16x32_bf16(a, b, c, 0, 0, 0);
}
static __device__ __forceinline__ f16_t mfma32(bf8_t a, bf8_t b, f16_t c) {
    return __builtin_amdgcn_mfma_f32_32x32x16_bf16(a, b, c, 0, 0, 0);
}
static __device__ __forceinline__ float sigf(float x) {
    return 1.0f / (1.0f + __expf(-x));
}
static __device__ __forceinline__ void gload_lds16(const void* g, void* l) {
    __builtin_amdgcn_global_load_lds(
        (const __attribute__((address_space(1))) void*)g,
        (__attribute__((address_space(3))) void*)l, 16, 0, 0);
}
static __device__ __forceinline__ uint32_t cvtpk(float lo, float hi) {
    uint32_t r;
    asm("v_cvt_pk_bf16_f32 %0, %1, %2" : "=v"(r) : "v"(lo), "v"(hi));
    return r;
}

// ---------------- kernel 0: convert x/h/W to bf16, build q-normalized x ----
__global__ __launch_bounds__(256) void k_convert(
    const float* __restrict__ x, const float* __restrict__ h,
    const float* __restrict__ W1, const float* __restrict__ W2,
    unsigned short* __restrict__ qn, unsigned short* __restrict__ xb,
    unsigned short* __restrict__ hb, unsigned short* __restrict__ w1b,
    unsigned short* __restrict__ w2b)
{
    __shared__ float sred[4];
    int bid = blockIdx.x, t = threadIdx.x;
    if (bid < 256) {
        float v = x[bid * 256 + t];
        float ss = v * v;
        #pragma unroll
        for (int m = 1; m < 64; m <<= 1) ss += __shfl_xor(ss, m, 64);
        if ((t & 63) == 0) sred[t >> 6] = ss;
        __syncthreads();
        float tot = sred[0] + sred[1] + sred[2] + sred[3];
        float rn = 1.0f / fmaxf(sqrtf(tot), 1e-8f);
        xb[bid * 256 + t] = fbf(v);
        qn[bid * 256 + t] = fbf(v * rn);
    } else if (bid < 512) {
        int b = bid - 256;
        hb[b * 256 + t] = fbf(h[b * 256 + t]);
    } else {
        int i0 = (bid - 512) * 256 + t;
        for (int i = i0; i < 1280 * 256; i += 512 * 256) {
            w1b[i] = fbf(W1[i]);
            w2b[i] = fbf(W2[i]);
        }
    }
}

// ---------------- kernel 1: preact = x@W1^T + h@W2^T + b1 + b2 --------------
__global__ __launch_bounds__(256) void k_gates(
    const unsigned short* __restrict__ xb, const unsigned short* __restrict__ hb,
    const unsigned short* __restrict__ w1b, const unsigned short* __restrict__ w2b,
    const float* __restrict__ b1, const float* __restrict__ b2,
    float* __restrict__ pre)
{
    int bb = (blockIdx.x & 3) * 64;
    int gb = (blockIdx.x >> 2) * 64;
    int t = threadIdx.x, w = t >> 6, lane = t & 63;
    int l15 = lane & 15, q8 = (lane >> 4) * 8, q4 = (lane >> 4) * 4;
    int arow = bb + w * 16 + l15;

    f4_t acc[4] = {};
    #pragma unroll
    for (int ks = 0; ks < 8; ++ks) {
        bf8_t a = *(const bf8_t*)&xb[arow * 256 + ks * 32 + q8];
        #pragma unroll
        for (int gc = 0; gc < 4; ++gc) {
            bf8_t bf = *(const bf8_t*)&w1b[(gb + gc * 16 + l15) * 256 + ks * 32 + q8];
            acc[gc] = mfma16(a, bf, acc[gc]);
        }
    }
    #pragma unroll
    for (int ks = 0; ks < 8; ++ks) {
        bf8_t a = *(const bf8_t*)&hb[arow * 256 + ks * 32 + q8];
        #pragma unroll
        for (int gc = 0; gc < 4; ++gc) {
            bf8_t bf = *(const bf8_t*)&w2b[(gb + gc * 16 + l15) * 256 + ks * 32 + q8];
            acc[gc] = mfma16(a, bf, acc[gc]);
        }
    }
    #pragma unroll
    for (int gc = 0; gc < 4; ++gc) {
        int g = gb + gc * 16 + l15;
        float bias = b1[g] + b2[g];
        #pragma unroll
        for (int r = 0; r < 4; ++r) {
            int b = bb + w * 16 + q4 + r;
            pre[b * 1280 + g] = acc[gc][r] + bias;
        }
    }
}

// ---------------- kernel P: keys -> normalized bf16, mfma32-swizzled tiles --
// Tile image: 32 rows x 512B. Element-chunk c (16B = 8 bf16, c=0..31) of row r
// stored at byte r*512 + ((c*16) ^ (r*16)). Full 32-slot XOR => the k_dnd
// GEMM1 A-frag read (lane=row) is bank-conflict-free.
__global__ __launch_bounds__(256) void k_prep(
    const float* __restrict__ keys, unsigned short* __restrict__ kn,
    int L, int CH, int TILES)
{
    int gt = blockIdx.x;
    int chunk = gt / TILES, tile = gt - chunk * TILES;
    int t = threadIdx.x;
    int r = t >> 3, j = t & 7;          // 8 threads per row; 32 floats each
    int grow = chunk * CH + tile * 32 + r;

    f4_t x[8];
    if (grow < L) {
        const float* src = keys + (size_t)grow * 256 + j * 32;
        #pragma unroll
        for (int k = 0; k < 8; ++k) x[k] = *(const f4_t*)(src + 4 * k);
    } else {
        #pragma unroll
        for (int k = 0; k < 8; ++k) x[k] = f4_t{0.f, 0.f, 0.f, 0.f};
    }
    float ss = 0.f;
    #pragma unroll
    for (int k = 0; k < 8; ++k)
        ss += x[k][0]*x[k][0] + x[k][1]*x[k][1] + x[k][2]*x[k][2] + x[k][3]*x[k][3];
    ss += __shfl_xor(ss, 1, 64);
    ss += __shfl_xor(ss, 2, 64);
    ss += __shfl_xor(ss, 4, 64);
    float rn = 1.0f / fmaxf(sqrtf(ss), 1e-8f);

    char* dst = (char*)kn + (size_t)gt * 16384 + r * 512;
    #pragma unroll
    for (int k2 = 0; k2 < 4; ++k2) {
        us8_t uv;
        #pragma unroll
        for (int e = 0; e < 4; ++e) {
            uv[e]     = fbf(x[2*k2][e] * rn);
            uv[e + 4] = fbf(x[2*k2 + 1][e] * rn);
        }
        *(us8_t*)(dst + ((j * 64 + k2 * 16) ^ (r * 16))) = uv;
    }
}

// ---------------- kernel 2: fused DND memory partials ------------------------
// 512 blocks = 256 chunks x 2 b-halves (twins on same XCD via bid&7 -> kn/V
// L2-shared). 256 threads, 4 waves; wave w owns b-rows bhalf*128+w*32..+31 x
// FULL 256 h (GEMM1 computed exactly once per (b,key) -> minimal MFMA work).
// K: pre-normalized bf16 staged via async global_load_lds (double-buffered,
// zero staging VGPRs). V: 32 volatile scalar loads/thread (h-column mapping
// -> 2-way-max LDS patterns at stride 152B), bf16-converted to Vb[h][key].
// In-register softmax (swapped GEMM1 + cvt_pk/permlane pack). 70KB LDS ->
// 2 blocks/CU; 2 barriers/tile; K always >= 1 tile of flight.
__global__ __launch_bounds__(256, 2) void k_dnd(
    const float* __restrict__ vals, const unsigned short* __restrict__ kn,
    const unsigned short* __restrict__ qn,
    unsigned short* __restrict__ opart, float* __restrict__ dpart,
    int L, int CH, int TILES)
{
    // Kb0 @0 (16KB) | Kb1 @16384 | Vb @32768 (256 rows x 152B = 38912)
    __shared__ __align__(16) char smem[71680];
    char* Vb = smem + 32768;

    const int t = threadIdx.x;
    const int w = t >> 6, lane = t & 63;
    const int l31 = lane & 31, hi = lane >> 5;

    const int bid = blockIdx.x;
    const int xcd = bid & 7;
    const int idx = bid >> 3;
    const int bhalf = idx & 1;
    const int chunk = (idx >> 1) * 8 + xcd;
    const int base = chunk * CH;
    int nk = L - base;
    if (nk > CH) nk = CH;
    if (nk < 0) nk = 0;
    const int nt = (nk + 31) >> 5;

    const int hcol = l31 + 32 * (w * 2 + hi);   // this thread's V column

    // Q fragments: B-operand of swapped GEMM1 (col b = l31)
    bf8_t qf[16];
    #pragma unroll
    for (int st = 0; st < 16; ++st)
        qf[st] = *(const bf8_t*)&qn[(bhalf * 128 + w * 32 + l31) * 256 + st * 16 + hi * 8];

    f16_t o[8] = {};
    float den = 0.f;
    float vst[32];

    auto issueK = [&](int tt) {
        const char* src = (const char*)kn + (size_t)(chunk * TILES + tt) * 16384
                        + w * 4096 + lane * 16;
        char* dst = smem + (tt & 1) * 16384 + w * 4096;
        #pragma unroll
        for (int c = 0; c < 4; ++c)
            gload_lds16(src + c * 1024, dst + c * 1024);
    };
    auto issueVa = [&](int tt) {
        int r0 = base + tt * 32;
        #pragma unroll
        for (int r = 0; r < 16; ++r) {
            int row = r0 + r;
            if (row >= L) row = L - 1;
            vst[r] = *(volatile const float*)&vals[(size_t)row * 256 + hcol];
        }
    };
    auto issueVb = [&](int tt) {
        int r0 = base + tt * 32;
        #pragma unroll
        for (int r = 16; r < 32; ++r) {
            int row = r0 + r;
            if (row >= L) row = L - 1;
            vst[r] = *(volatile const float*)&vals[(size_t)row * 256 + hcol];
        }
    };
    auto convertV = [&]() {
        #pragma unroll
        for (int q = 0; q < 8; ++q) {
            union { uint32_t u[2]; us4_t s; } pv;
            pv.u[0] = cvtpk(vst[4*q],     vst[4*q + 1]);
            pv.u[1] = cvtpk(vst[4*q + 2], vst[4*q + 3]);
            *(us4_t*)(Vb + hcol * 152 + q * 8) = pv.s;
        }
    };

    if (nt > 0) {
        issueK(0);
        issueVa(0); issueVb(0);
        asm volatile("s_waitcnt vmcnt(0)" ::: "memory");
        convertV();
        issueK(nt > 1 ? 1 : 0);
        asm volatile("s_waitcnt lgkmcnt(0)\n\ts_barrier" ::: "memory");

        for (int tt = 0; tt < nt; ++tt) {
            int tn = tt + 1 < nt ? tt + 1 : nt - 1;
            issueVa(tn);
            __builtin_amdgcn_sched_barrier(0);

            const char* Kb = smem + (tt & 1) * 16384;

            // ---- GEMM1 (swapped): S[l][b] = K @ Q^T, 16 d-steps ----
            f16_t sc = {};
            __builtin_amdgcn_s_setprio(1);
            #pragma unroll
            for (int st = 0; st < 16; ++st) {
                bf8_t kf = *(const bf8_t*)(Kb + l31 * 512 +
                               (((2 * st + hi) * 16) ^ (l31 * 16)));
                sc = mfma32(kf, qf[st], sc);
            }
            __builtin_amdgcn_s_setprio(0);

            issueVb(tn);
            __builtin_amdgcn_sched_barrier(0);

            // ---- softmax in-register: p = exp(s-1) (sims in [-1,1]) ----
            float p[16];
            bool full = (tt * 32 + 32 <= nk);
            #pragma unroll
            for (int r = 0; r < 16; ++r) {
                int l = (r & 3) + 8 * (r >> 2) + 4 * hi;
                float pv = __expf(sc[r] - 1.0f);
                if (!full && (tt * 32 + l) >= nk) pv = 0.f;
                p[r] = pv;
                den += pv;
            }
            uint32_t a0 = cvtpk(p[0], p[1]),   a1 = cvtpk(p[2], p[3]);
            uint32_t b0 = cvtpk(p[4], p[5]),   b1 = cvtpk(p[6], p[7]);
            uint32_t c0 = cvtpk(p[8], p[9]),   c1 = cvtpk(p[10], p[11]);
            uint32_t d0 = cvtpk(p[12], p[13]), d1 = cvtpk(p[14], p[15]);
            asm("v_permlane32_swap_b32 %0, %1" : "+v"(a0), "+v"(b0));
            asm("v_permlane32_swap_b32 %0, %1" : "+v"(a1), "+v"(b1));
            asm("v_permlane32_swap_b32 %0, %1" : "+v"(c0), "+v"(d0));
            asm("v_permlane32_swap_b32 %0, %1" : "+v"(c1), "+v"(d1));
            union { uint32_t u[4]; bf8_t v; } pa0, pa1;
            pa0.u[0] = a0; pa0.u[1] = a1; pa0.u[2] = b0; pa0.u[3] = b1;
            pa1.u[0] = c0; pa1.u[1] = c1; pa1.u[2] = d0; pa1.u[3] = d1;

            // ---- GEMM2: O[b][h] += P @ V (8 h-groups x 2 kslices) ----
            __builtin_amdgcn_s_setprio(1);
            #pragma unroll
            for (int g = 0; g < 8; ++g) {
                const char* vb = Vb + (g * 32 + l31) * 152 + hi * 16;
                union { us4_t h[2]; bf8_t v; } vf0, vf1;
                vf0.h[0] = *(const us4_t*)(vb);
                vf0.h[1] = *(const us4_t*)(vb + 8);
                vf1.h[0] = *(const us4_t*)(vb + 32);
                vf1.h[1] = *(const us4_t*)(vb + 40);
                o[g] = mfma32(pa0.v, vf0.v, o[g]);
                o[g] = mfma32(pa1.v, vf1.v, o[g]);
            }
            __builtin_amdgcn_s_setprio(0);

            asm volatile("s_waitcnt lgkmcnt(0)\n\ts_barrier" ::: "memory");

            if (tt + 1 < nt) {
                asm volatile("s_waitcnt vmcnt(0)" ::: "memory");  // V(t+1)+K(t+1) landed
                convertV();
                issueK(tt + 2 < nt ? tt + 2 : nt - 1);
                asm volatile("s_waitcnt lgkmcnt(0)\n\ts_barrier" ::: "memory");
            }
        }
    }

    // ---- epilogue: drain, LDS transpose -> coalesced stores, den ----
    asm volatile("s_waitcnt vmcnt(0)" ::: "memory");
    __syncthreads();
    unsigned short* Ol = (unsigned short*)smem;   // [128 b][256 h]
    #pragma unroll
    for (int g = 0; g < 8; ++g)
        #pragma unroll
        for (int r = 0; r < 16; ++r) {
            int b = w * 32 + (r & 3) + 8 * (r >> 2) + 4 * hi;
            Ol[b * 256 + g * 32 + l31] = fbf(o[g][r]);
        }
    __syncthreads();
    {
        size_t ob = (size_t)(chunk * 2 + bhalf) * 32768;
        #pragma unroll
        for (int it = 0; it < 16; ++it) {
            int off = it * 2048 + t * 8;
            *(us8_t*)&opart[ob + off] = *(const us8_t*)&Ol[off];
        }
    }
    den += __shfl_xor(den, 32, 64);
    if (hi == 0)
        dpart[chunk * 256 + bhalf * 128 + w * 32 + l31] = den;
}

// ---------------- kernel 3: reduce partials + LSTM epilogue -----------------
__global__ __launch_bounds__(256) void k_reduce(
    const unsigned short* __restrict__ opart, const float* __restrict__ dpart,
    const float* __restrict__ pre, const float* __restrict__ c_in,
    float* __restrict__ out)
{
    __shared__ float sred[4];
    int b = blockIdx.x, t = threadIdx.x;

    float ds = dpart[t * 256 + b];
    #pragma unroll
    for (int m = 1; m < 64; m <<= 1) ds += __shfl_xor(ds, m, 64);
    if ((t & 63) == 0) sred[t >> 6] = ds;
    __syncthreads();
    float dtot = fmaxf(sred[0] + sred[1] + sred[2] + sred[3], 1e-30f);

    int bh = b >> 7, br = b & 127;
    size_t sb = (size_t)br * 256 + t;
    float n0 = 0.f, n1 = 0.f, n2 = 0.f, n3 = 0.f;
    for (int ck = 0; ck < 256; ck += 4) {
        n0 += bf2f(opart[(size_t)((ck + 0) * 2 + bh) * 32768 + sb]);
        n1 += bf2f(opart[(size_t)((ck + 1) * 2 + bh) * 32768 + sb]);
        n2 += bf2f(opart[(size_t)((ck + 2) * 2 + bh) * 32768 + sb]);
        n3 += bf2f(opart[(size_t)((ck + 3) * 2 + bh) * 32768 + sb]);
    }
    float num = (n0 + n1) + (n2 + n3);

    float m = tanhf(num / dtot);
    const float* p = pre + b * 1280;
    float fg = sigf(p[t]);
    float ig = sigf(p[256 + t]);
    float og = sigf(p[512 + t]);
    float rg = sigf(p[768 + t]);
    float cn = tanhf(p[1024 + t]);
    float co = c_in[b * 256 + t];
    float ct = fg * co + ig * cn + rg * m;
    float ht = og * tanhf(ct);
    out[b * 256 + t] = ht;
    out[65536 + b * 256 + t] = ct;
}

// ---------------- launch ----------------------------------------------------
extern "C" void kernel_launch(void* const* d_in, const int* in_sizes, int n_in,
                              void* d_out, int out_size, void* d_ws, size_t ws_size,
                              hipStream_t stream)
{
    const float* x    = (const float*)d_in[0];
    const float* h    = (const float*)d_in[1];
    const float* c    = (const float*)d_in[2];
    const float* W1   = (const float*)d_in[3];
    const float* b1   = (const float*)d_in[4];
    const float* W2   = (const float*)d_in[5];
    const float* b2   = (const float*)d_in[6];
    const float* keys = (const float*)d_in[7];
    const float* vals = (const float*)d_in[8];
    int L = in_sizes[7] / 256;

    // 256 chunks, each a multiple of 32 keys
    int TILES = (L + 256 * 32 - 1) / (256 * 32);
    int CH = TILES * 32;

    char* ws = (char*)d_ws;
    unsigned short* qn    = (unsigned short*)(ws + 0);
    unsigned short* xb    = (unsigned short*)(ws + 131072);
    unsigned short* hb    = (unsigned short*)(ws + 262144);
    unsigned short* w1b   = (unsigned short*)(ws + 393216);
    unsigned short* w2b   = (unsigned short*)(ws + 1048576);
    float*          pre   = (float*)(ws + 1703936);
    float*          dpart = (float*)(ws + 3014656);   // 256*256 f32
    unsigned short* kn    = (unsigned short*)(ws + 3276800);
    unsigned short* opart = (unsigned short*)(ws + 3276800 + (size_t)256 * TILES * 16384);

    k_convert<<<dim3(1024), dim3(256), 0, stream>>>(x, h, W1, W2, qn, xb, hb, w1b, w2b);
    k_gates<<<dim3(80), dim3(256), 0, stream>>>(xb, hb, w1b, w2b, b1, b2, pre);
    k_prep<<<dim3(256 * TILES), dim3(256), 0, stream>>>(keys, kn, L, CH, TILES);
    k_dnd<<<dim3(512), dim3(256), 0, stream>>>(vals, kn, qn, opart, dpart, L, CH, TILES);
    k_reduce<<<dim3(256), dim3(256), 0, stream>>>(opart, dpart, pre, c, (float*)d_out);

    (void)n_in; (void)out_size; (void)ws_size;
}

// Round 13
// 216.353 us; speedup vs baseline: 1.4136x; 1.4136x over previous
//
#include <hip/hip_runtime.h>
#include <stdint.h>

typedef float f4_t __attribute__((ext_vector_type(4)));
typedef float f16_t __attribute__((ext_vector_type(16)));
typedef __bf16 bf8_t __attribute__((ext_vector_type(8)));
typedef unsigned short us4_t __attribute__((ext_vector_type(4)));
typedef unsigned short us8_t __attribute__((ext_vector_type(8)));

#define NCH 224            // chunks (k_dnd blocks); 224*7*64 = 100352 key slots

static __device__ __forceinline__ unsigned short fbf(float f) {
    __bf16 b = (__bf16)f;
    return *(unsigned short*)&b;
}
static __device__ __forceinline__ float bf2f(unsigned short u) {
    union { uint32_t u; float f; } v; v.u = ((uint32_t)u) << 16;
    return v.f;
}
static __device__ __forceinline__ f4_t mfma16(bf8_t a, bf8_t b, f4_t c) {
    return __builtin_amdgcn_mfma_f32_16x16x32_bf16(a, b, c, 0, 0, 0);
}
static __device__ __forceinline__ f16_t mfma32(bf8_t a, bf8_t b, f16_t c) {
    return __builtin_amdgcn_mfma_f32_32x32x16_bf16(a, b, c, 0, 0, 0);
}
static __device__ __forceinline__ float sigf(float x) {
    return 1.0f / (1.0f + __expf(-x));
}
static __device__ __forceinline__ void gload_lds16(const void* g, void* l) {
    __builtin_amdgcn_global_load_lds(
        (const __attribute__((address_space(1))) void*)g,
        (__attribute__((address_space(3))) void*)l, 16, 0, 0);
}
static __device__ __forceinline__ uint32_t cvtpk(float lo, float hi) {
    uint32_t r;
    asm("v_cvt_pk_bf16_f32 %0, %1, %2" : "=v"(r) : "v"(lo), "v"(hi));
    return r;
}

// ---------------- kernel 0: convert x/h/W to bf16, build q-normalized x ----
__global__ __launch_bounds__(256) void k_convert(
    const float* __restrict__ x, const float* __restrict__ h,
    const float* __restrict__ W1, const float* __restrict__ W2,
    unsigned short* __restrict__ qn, unsigned short* __restrict__ xb,
    unsigned short* __restrict__ hb, unsigned short* __restrict__ w1b,
    unsigned short* __restrict__ w2b)
{
    __shared__ float sred[4];
    int bid = blockIdx.x, t = threadIdx.x;
    if (bid < 256) {
        float v = x[bid * 256 + t];
        float ss = v * v;
        #pragma unroll
        for (int m = 1; m < 64; m <<= 1) ss += __shfl_xor(ss, m, 64);
        if ((t & 63) == 0) sred[t >> 6] = ss;
        __syncthreads();
        float tot = sred[0] + sred[1] + sred[2] + sred[3];
        float rn = 1.0f / fmaxf(sqrtf(tot), 1e-8f);
        xb[bid * 256 + t] = fbf(v);
        qn[bid * 256 + t] = fbf(v * rn);
    } else if (bid < 512) {
        int b = bid - 256;
        hb[b * 256 + t] = fbf(h[b * 256 + t]);
    } else {
        int i0 = (bid - 512) * 256 + t;
        for (int i = i0; i < 1280 * 256; i += 512 * 256) {
            w1b[i] = fbf(W1[i]);
            w2b[i] = fbf(W2[i]);
        }
    }
}

// ---------------- kernel 1: preact = x@W1^T + h@W2^T + b1 + b2 --------------
__global__ __launch_bounds__(256) void k_gates(
    const unsigned short* __restrict__ xb, const unsigned short* __restrict__ hb,
    const unsigned short* __restrict__ w1b, const unsigned short* __restrict__ w2b,
    const float* __restrict__ b1, const float* __restrict__ b2,
    float* __restrict__ pre)
{
    int bb = (blockIdx.x & 3) * 64;
    int gb = (blockIdx.x >> 2) * 64;
    int t = threadIdx.x, w = t >> 6, lane = t & 63;
    int l15 = lane & 15, q8 = (lane >> 4) * 8, q4 = (lane >> 4) * 4;
    int arow = bb + w * 16 + l15;

    f4_t acc[4] = {};
    #pragma unroll
    for (int ks = 0; ks < 8; ++ks) {
        bf8_t a = *(const bf8_t*)&xb[arow * 256 + ks * 32 + q8];
        #pragma unroll
        for (int gc = 0; gc < 4; ++gc) {
            bf8_t bf = *(const bf8_t*)&w1b[(gb + gc * 16 + l15) * 256 + ks * 32 + q8];
            acc[gc] = mfma16(a, bf, acc[gc]);
        }
    }
    #pragma unroll
    for (int ks = 0; ks < 8; ++ks) {
        bf8_t a = *(const bf8_t*)&hb[arow * 256 + ks * 32 + q8];
        #pragma unroll
        for (int gc = 0; gc < 4; ++gc) {
            bf8_t bf = *(const bf8_t*)&w2b[(gb + gc * 16 + l15) * 256 + ks * 32 + q8];
            acc[gc] = mfma16(a, bf, acc[gc]);
        }
    }
    #pragma unroll
    for (int gc = 0; gc < 4; ++gc) {
        int g = gb + gc * 16 + l15;
        float bias = b1[g] + b2[g];
        #pragma unroll
        for (int r = 0; r < 4; ++r) {
            int b = bb + w * 16 + q4 + r;
            pre[b * 1280 + g] = acc[gc][r] + bias;
        }
    }
}

// ---------------- kernel P: K AND V -> MFMA-ready bf16 images ---------------
// Per 64-key tile (one block):
//  K image (32KB): 2 groups of 32 rows x 512B; 16B chunk c of row r at
//    byte grp*16384 + r*512 + ((c*16) ^ (r*16))   [full-XOR: 0 conflicts]
//  V image (32KB): transposed [h=256][k=64] bf16, row h at h*128; 8B slot q
//    at ((q ^ (h&15))*8)                          [16-start XOR: 2-way max]
__global__ __launch_bounds__(256) void k_prep(
    const float* __restrict__ keys, const float* __restrict__ vals,
    unsigned short* __restrict__ kn, unsigned short* __restrict__ vbuf,
    int L, int CH, int TILES)
{
    const int bt = blockIdx.x;
    const int t = threadIdx.x;
    const int key0 = (bt / TILES) * CH + (bt % TILES) * 64;

    // ---- K part: 8 threads/row, 2 groups ----
    {
        const int r = t >> 3, j = t & 7;
        char* kdst = (char*)kn + (size_t)bt * 32768;
        #pragma unroll
        for (int grp = 0; grp < 2; ++grp) {
            int grow = key0 + grp * 32 + r;
            f4_t x[8];
            if (grow < L) {
                const float* src = keys + (size_t)grow * 256 + j * 32;
                #pragma unroll
                for (int k = 0; k < 8; ++k) x[k] = *(const f4_t*)(src + 4 * k);
            } else {
                #pragma unroll
                for (int k = 0; k < 8; ++k) x[k] = f4_t{0.f, 0.f, 0.f, 0.f};
            }
            float ss = 0.f;
            #pragma unroll
            for (int k = 0; k < 8; ++k)
                ss += x[k][0]*x[k][0] + x[k][1]*x[k][1]
                    + x[k][2]*x[k][2] + x[k][3]*x[k][3];
            ss += __shfl_xor(ss, 1, 64);
            ss += __shfl_xor(ss, 2, 64);
            ss += __shfl_xor(ss, 4, 64);
            float rn = 1.0f / fmaxf(sqrtf(ss), 1e-8f);
            char* gd = kdst + grp * 16384 + r * 512;
            #pragma unroll
            for (int k2 = 0; k2 < 4; ++k2) {
                us8_t uv;
                #pragma unroll
                for (int e = 0; e < 4; ++e) {
                    uv[e]     = fbf(x[2*k2][e]     * rn);
                    uv[e + 4] = fbf(x[2*k2 + 1][e] * rn);
                }
                *(us8_t*)(gd + ((j * 64 + k2 * 16) ^ (r * 16))) = uv;
            }
        }
    }
    // ---- V part: thread t = h column; reads 64 keys (coalesced across h) ----
    {
        char* vdst = (char*)vbuf + (size_t)bt * 32768 + t * 128;
        const int x15 = t & 15;
        float v[64];
        #pragma unroll
        for (int k = 0; k < 64; ++k) {
            int row = key0 + k;
            v[k] = (row < L) ? vals[(size_t)row * 256 + t] : 0.0f;
        }
        #pragma unroll
        for (int q = 0; q < 16; ++q) {
            union { uint32_t u[2]; us4_t s; } pv;
            pv.u[0] = cvtpk(v[4*q],     v[4*q + 1]);
            pv.u[1] = cvtpk(v[4*q + 2], v[4*q + 3]);
            *(us4_t*)(vdst + ((q ^ x15) * 8)) = pv.s;
        }
    }
}

// ---------------- kernel 2: DND partials — pure gload_lds MFMA pipeline -----
// 224 blocks (1/CU), 512 threads = 8 waves; wave w owns b = w*32..+31 x 256 h.
// 64-key tiles; K (32KB) + V (32KB) double-buffered = 128KB LDS. Per tile per
// wave: 8 gload_lds (4 K + 4 V) -> counted vmcnt(8) -> barrier. ZERO inline
// conversion. GEMM1 swapped mfma32 (S[l][b], lane=b) + in-register softmax
// (T12 cvt_pk + permlane32_swap) + GEMM2. Each kn/vb byte fetched once.
__global__ __launch_bounds__(512, 2) void k_dnd(
    const unsigned short* __restrict__ kn, const unsigned short* __restrict__ vbuf,
    const unsigned short* __restrict__ qn,
    unsigned short* __restrict__ opart, float* __restrict__ dpart,
    int L, int CH, int TILES)
{
    // Kbuf0 @0 | Kbuf1 @32768 | Vbuf0 @65536 | Vbuf1 @98304   (128KB)
    __shared__ __align__(16) char smem[131072];

    const int t = threadIdx.x;
    const int w = t >> 6, lane = t & 63;
    const int l31 = lane & 31, hi = lane >> 5;

    const int chunk = blockIdx.x;
    const int base = chunk * CH;
    int nk = L - base;
    if (nk > CH) nk = CH;
    if (nk < 0) nk = 0;
    const int nt = (nk + 63) >> 6;

    // Q fragments: B-operand of swapped GEMM1 (col b = w*32 + l31)
    bf8_t qf[16];
    #pragma unroll
    for (int st = 0; st < 16; ++st)
        qf[st] = *(const bf8_t*)&qn[(w * 32 + l31) * 256 + st * 16 + hi * 8];
    asm volatile("s_waitcnt vmcnt(0)" ::: "memory");   // qf resolved; vmcnt
                                                       // now counts only DMAs
    f16_t o[8] = {};
    float den = 0.f;

    auto issue = [&](int tt) {
        size_t goff = (size_t)(chunk * TILES + tt) * 32768 + w * 4096;
        const char* ks = (const char*)kn + goff + lane * 16;
        const char* vs = (const char*)vbuf + goff + lane * 16;
        char* kd = smem + (tt & 1) * 32768 + w * 4096;
        char* vd = smem + 65536 + (tt & 1) * 32768 + w * 4096;
        #pragma unroll
        for (int c = 0; c < 4; ++c) gload_lds16(ks + c * 1024, kd + c * 1024);
        #pragma unroll
        for (int c = 0; c < 4; ++c) gload_lds16(vs + c * 1024, vd + c * 1024);
    };

    if (nt > 0) {
        issue(0);
        if (nt > 1) {
            issue(1);
            asm volatile("s_waitcnt vmcnt(8)" ::: "memory");
        } else {
            asm volatile("s_waitcnt vmcnt(0)" ::: "memory");
        }
        asm volatile("s_barrier" ::: "memory");

        for (int tt = 0; tt < nt; ++tt) {
            const char* Kb = smem + (tt & 1) * 32768;
            const char* Vb = smem + 65536 + (tt & 1) * 32768;

            #pragma unroll
            for (int u = 0; u < 2; ++u) {
                // ---- GEMM1 (swapped): S[l][b] = K @ Q^T, 16 d-steps ----
                f16_t sc = {};
                __builtin_amdgcn_s_setprio(1);
                #pragma unroll
                for (int st = 0; st < 16; ++st) {
                    bf8_t kf = *(const bf8_t*)(Kb + u * 16384 + l31 * 512 +
                                   (((2 * st + hi) * 16) ^ (l31 * 16)));
                    sc = mfma32(kf, qf[st], sc);
                }
                __builtin_amdgcn_s_setprio(0);

                // ---- in-register softmax: p = exp(s-1) (sims in [-1,1]) ----
                float p[16];
                int kbase = tt * 64 + u * 32;
                bool full = (kbase + 32 <= nk);
                #pragma unroll
                for (int r = 0; r < 16; ++r) {
                    int l = (r & 3) + 8 * (r >> 2) + 4 * hi;
                    float pv = __expf(sc[r] - 1.0f);
                    if (!full && (kbase + l) >= nk) pv = 0.f;
                    p[r] = pv;
                    den += pv;
                }
                uint32_t a0 = cvtpk(p[0], p[1]),   a1 = cvtpk(p[2], p[3]);
                uint32_t b0 = cvtpk(p[4], p[5]),   b1 = cvtpk(p[6], p[7]);
                uint32_t c0 = cvtpk(p[8], p[9]),   c1 = cvtpk(p[10], p[11]);
                uint32_t d0 = cvtpk(p[12], p[13]), d1 = cvtpk(p[14], p[15]);
                asm("v_permlane32_swap_b32 %0, %1" : "+v"(a0), "+v"(b0));
                asm("v_permlane32_swap_b32 %0, %1" : "+v"(a1), "+v"(b1));
                asm("v_permlane32_swap_b32 %0, %1" : "+v"(c0), "+v"(d0));
                asm("v_permlane32_swap_b32 %0, %1" : "+v"(c1), "+v"(d1));
                union { uint32_t u4[4]; bf8_t v; } pa0, pa1;
                pa0.u4[0] = a0; pa0.u4[1] = a1; pa0.u4[2] = b0; pa0.u4[3] = b1;
                pa1.u4[0] = c0; pa1.u4[1] = c1; pa1.u4[2] = d0; pa1.u4[3] = d1;

                // ---- GEMM2: O[b][h] += P @ V (8 h-groups x 2 k-slices) ----
                __builtin_amdgcn_s_setprio(1);
                #pragma unroll
                for (int g = 0; g < 8; ++g) {
                    int hh = g * 32 + l31;
                    const char* vr = Vb + hh * 128;
                    int x15 = hh & 15;
                    int s0 = 8 * u + 2 * hi;
                    union { us4_t h4[2]; bf8_t v; } vf0, vf1;
                    vf0.h4[0] = *(const us4_t*)(vr + (((s0 + 0) ^ x15) * 8));
                    vf0.h4[1] = *(const us4_t*)(vr + (((s0 + 1) ^ x15) * 8));
                    vf1.h4[0] = *(const us4_t*)(vr + (((s0 + 4) ^ x15) * 8));
                    vf1.h4[1] = *(const us4_t*)(vr + (((s0 + 5) ^ x15) * 8));
                    o[g] = mfma32(pa0.v, vf0.v, o[g]);
                    o[g] = mfma32(pa1.v, vf1.v, o[g]);
                }
                __builtin_amdgcn_s_setprio(0);
            }

            // ---- sync: free buf[tt&1], prefetch t+2, ensure t+1 landed ----
            asm volatile("s_waitcnt lgkmcnt(0)\n\ts_barrier" ::: "memory");
            if (tt + 2 < nt) {
                issue(tt + 2);
                asm volatile("s_waitcnt vmcnt(8)" ::: "memory");
            } else {
                asm volatile("s_waitcnt vmcnt(0)" ::: "memory");
            }
            asm volatile("s_barrier" ::: "memory");
        }
    }

    // ---- epilogue: LDS transpose -> coalesced stores; den combine ----
    asm volatile("s_waitcnt vmcnt(0)" ::: "memory");
    __syncthreads();
    unsigned short* Ol = (unsigned short*)smem;   // [256 b][256 h] = 128KB
    #pragma unroll
    for (int g = 0; g < 8; ++g)
        #pragma unroll
        for (int r = 0; r < 16; ++r) {
            int b = w * 32 + (r & 3) + 8 * (r >> 2) + 4 * hi;
            Ol[b * 256 + g * 32 + l31] = fbf(o[g][r]);
        }
    __syncthreads();
    {
        size_t ob = (size_t)chunk * 65536;
        #pragma unroll
        for (int it = 0; it < 16; ++it) {
            int off = it * 4096 + t * 8;
            *(us8_t*)&opart[ob + off] = *(const us8_t*)&Ol[off];
        }
    }
    den += __shfl_xor(den, 32, 64);
    if (hi == 0)
        dpart[chunk * 256 + w * 32 + l31] = den;
}

// ---------------- kernel 3: reduce partials + LSTM epilogue -----------------
__global__ __launch_bounds__(256) void k_reduce(
    const unsigned short* __restrict__ opart, const float* __restrict__ dpart,
    const float* __restrict__ pre, const float* __restrict__ c_in,
    float* __restrict__ out)
{
    __shared__ float sred[4];
    int b = blockIdx.x, t = threadIdx.x;

    float ds = (t < NCH) ? dpart[t * 256 + b] : 0.0f;
    #pragma unroll
    for (int m = 1; m < 64; m <<= 1) ds += __shfl_xor(ds, m, 64);
    if ((t & 63) == 0) sred[t >> 6] = ds;
    __syncthreads();
    float dtot = fmaxf(sred[0] + sred[1] + sred[2] + sred[3], 1e-30f);

    size_t sb = (size_t)b * 256 + t;
    float n0 = 0.f, n1 = 0.f, n2 = 0.f, n3 = 0.f;
    for (int ck = 0; ck < NCH; ck += 4) {
        n0 += bf2f(opart[(size_t)(ck + 0) * 65536 + sb]);
        n1 += bf2f(opart[(size_t)(ck + 1) * 65536 + sb]);
        n2 += bf2f(opart[(size_t)(ck + 2) * 65536 + sb]);
        n3 += bf2f(opart[(size_t)(ck + 3) * 65536 + sb]);
    }
    float num = (n0 + n1) + (n2 + n3);

    float m = tanhf(num / dtot);
    const float* p = pre + b * 1280;
    float fg = sigf(p[t]);
    float ig = sigf(p[256 + t]);
    float og = sigf(p[512 + t]);
    float rg = sigf(p[768 + t]);
    float cn = tanhf(p[1024 + t]);
    float co = c_in[b * 256 + t];
    float ct = fg * co + ig * cn + rg * m;
    float ht = og * tanhf(ct);
    out[b * 256 + t] = ht;
    out[65536 + b * 256 + t] = ct;
}

// ---------------- launch ----------------------------------------------------
extern "C" void kernel_launch(void* const* d_in, const int* in_sizes, int n_in,
                              void* d_out, int out_size, void* d_ws, size_t ws_size,
                              hipStream_t stream)
{
    const float* x    = (const float*)d_in[0];
    const float* h    = (const float*)d_in[1];
    const float* c    = (const float*)d_in[2];
    const float* W1   = (const float*)d_in[3];
    const float* b1   = (const float*)d_in[4];
    const float* W2   = (const float*)d_in[5];
    const float* b2   = (const float*)d_in[6];
    const float* keys = (const float*)d_in[7];
    const float* vals = (const float*)d_in[8];
    int L = in_sizes[7] / 256;

    // NCH chunks, each TILES tiles of 64 keys
    int TILES = (L + NCH * 64 - 1) / (NCH * 64);      // 7 for L=100000
    int CH = TILES * 64;                              // 448
    int NT = NCH * TILES;                             // total tiles = 1568

    char* ws = (char*)d_ws;
    unsigned short* qn    = (unsigned short*)(ws + 0);
    unsigned short* xb    = (unsigned short*)(ws + 131072);
    unsigned short* hb    = (unsigned short*)(ws + 262144);
    unsigned short* w1b   = (unsigned short*)(ws + 393216);
    unsigned short* w2b   = (unsigned short*)(ws + 1048576);
    float*          pre   = (float*)(ws + 1703936);
    float*          dpart = (float*)(ws + 3014656);              // NCH*256 f32
    unsigned short* kn    = (unsigned short*)(ws + 3276800);
    unsigned short* vb    = (unsigned short*)(ws + 3276800 + (size_t)NT * 32768);
    unsigned short* opart = (unsigned short*)(ws + 3276800 + (size_t)NT * 65536);

    k_convert<<<dim3(1024), dim3(256), 0, stream>>>(x, h, W1, W2, qn, xb, hb, w1b, w2b);
    k_gates<<<dim3(80), dim3(256), 0, stream>>>(xb, hb, w1b, w2b, b1, b2, pre);
    k_prep<<<dim3(NT), dim3(256), 0, stream>>>(keys, vals, kn, vb, L, CH, TILES);
    k_dnd<<<dim3(NCH), dim3(512), 0, stream>>>(kn, vb, qn, opart, dpart, L, CH, TILES);
    k_reduce<<<dim3(256), dim3(256), 0, stream>>>(opart, dpart, pre, c, (float*)d_out);

    (void)n_in; (void)out_size; (void)ws_size;
}

// Round 14
// 201.606 us; speedup vs baseline: 1.5170x; 1.0731x over previous
//
#include <hip/hip_runtime.h>
#include <stdint.h>

typedef float f4_t __attribute__((ext_vector_type(4)));
typedef float f16_t __attribute__((ext_vector_type(16)));
typedef __bf16 bf8_t __attribute__((ext_vector_type(8)));
typedef unsigned short us4_t __attribute__((ext_vector_type(4)));
typedef unsigned short us8_t __attribute__((ext_vector_type(8)));

#define NCH 224            // chunks (k_dnd blocks); 224*7*64 = 100352 key slots

static __device__ __forceinline__ unsigned short fbf(float f) {
    __bf16 b = (__bf16)f;
    return *(unsigned short*)&b;
}
static __device__ __forceinline__ float bf2f(unsigned short u) {
    union { uint32_t u; float f; } v; v.u = ((uint32_t)u) << 16;
    return v.f;
}
static __device__ __forceinline__ f4_t mfma16(bf8_t a, bf8_t b, f4_t c) {
    return __builtin_amdgcn_mfma_f32_16x16x32_bf16(a, b, c, 0, 0, 0);
}
static __device__ __forceinline__ f16_t mfma32(bf8_t a, bf8_t b, f16_t c) {
    return __builtin_amdgcn_mfma_f32_32x32x16_bf16(a, b, c, 0, 0, 0);
}
static __device__ __forceinline__ float sigf(float x) {
    return 1.0f / (1.0f + __expf(-x));
}
static __device__ __forceinline__ void gload_lds16(const void* g, void* l) {
    __builtin_amdgcn_global_load_lds(
        (const __attribute__((address_space(1))) void*)g,
        (__attribute__((address_space(3))) void*)l, 16, 0, 0);
}
static __device__ __forceinline__ uint32_t cvtpk(float lo, float hi) {
    uint32_t r;
    asm("v_cvt_pk_bf16_f32 %0, %1, %2" : "=v"(r) : "v"(lo), "v"(hi));
    return r;
}

// ---------------- kernel 0: convert x/h/W to bf16, build q-normalized x ----
__global__ __launch_bounds__(256) void k_convert(
    const float* __restrict__ x, const float* __restrict__ h,
    const float* __restrict__ W1, const float* __restrict__ W2,
    unsigned short* __restrict__ qn, unsigned short* __restrict__ xb,
    unsigned short* __restrict__ hb, unsigned short* __restrict__ w1b,
    unsigned short* __restrict__ w2b)
{
    __shared__ float sred[4];
    int bid = blockIdx.x, t = threadIdx.x;
    if (bid < 256) {
        float v = x[bid * 256 + t];
        float ss = v * v;
        #pragma unroll
        for (int m = 1; m < 64; m <<= 1) ss += __shfl_xor(ss, m, 64);
        if ((t & 63) == 0) sred[t >> 6] = ss;
        __syncthreads();
        float tot = sred[0] + sred[1] + sred[2] + sred[3];
        float rn = 1.0f / fmaxf(sqrtf(tot), 1e-8f);
        xb[bid * 256 + t] = fbf(v);
        qn[bid * 256 + t] = fbf(v * rn);
    } else if (bid < 512) {
        int b = bid - 256;
        hb[b * 256 + t] = fbf(h[b * 256 + t]);
    } else {
        int i0 = (bid - 512) * 256 + t;
        for (int i = i0; i < 1280 * 256; i += 512 * 256) {
            w1b[i] = fbf(W1[i]);
            w2b[i] = fbf(W2[i]);
        }
    }
}

// ---------------- kernel 1: preact = x@W1^T + h@W2^T + b1 + b2 --------------
__global__ __launch_bounds__(256) void k_gates(
    const unsigned short* __restrict__ xb, const unsigned short* __restrict__ hb,
    const unsigned short* __restrict__ w1b, const unsigned short* __restrict__ w2b,
    const float* __restrict__ b1, const float* __restrict__ b2,
    float* __restrict__ pre)
{
    int bb = (blockIdx.x & 3) * 64;
    int gb = (blockIdx.x >> 2) * 64;
    int t = threadIdx.x, w = t >> 6, lane = t & 63;
    int l15 = lane & 15, q8 = (lane >> 4) * 8, q4 = (lane >> 4) * 4;
    int arow = bb + w * 16 + l15;

    f4_t acc[4] = {};
    #pragma unroll
    for (int ks = 0; ks < 8; ++ks) {
        bf8_t a = *(const bf8_t*)&xb[arow * 256 + ks * 32 + q8];
        #pragma unroll
        for (int gc = 0; gc < 4; ++gc) {
            bf8_t bf = *(const bf8_t*)&w1b[(gb + gc * 16 + l15) * 256 + ks * 32 + q8];
            acc[gc] = mfma16(a, bf, acc[gc]);
        }
    }
    #pragma unroll
    for (int ks = 0; ks < 8; ++ks) {
        bf8_t a = *(const bf8_t*)&hb[arow * 256 + ks * 32 + q8];
        #pragma unroll
        for (int gc = 0; gc < 4; ++gc) {
            bf8_t bf = *(const bf8_t*)&w2b[(gb + gc * 16 + l15) * 256 + ks * 32 + q8];
            acc[gc] = mfma16(a, bf, acc[gc]);
        }
    }
    #pragma unroll
    for (int gc = 0; gc < 4; ++gc) {
        int g = gb + gc * 16 + l15;
        float bias = b1[g] + b2[g];
        #pragma unroll
        for (int r = 0; r < 4; ++r) {
            int b = bb + w * 16 + q4 + r;
            pre[b * 1280 + g] = acc[gc][r] + bias;
        }
    }
}

// ---------------- kernel P: K AND V -> MFMA-ready bf16 images ---------------
// Per 64-key tile (one block, 256 threads):
//  K image (32KB): 2 groups of 32 rows x 512B; 16B chunk c of row r at
//    byte grp*16384 + r*512 + ((c*16) ^ (r*16))   [full-XOR: 0 conflicts]
//  V image (32KB): transposed [h=256][k=64] bf16, row h at h*128; 8B slot q
//    (keys 4q..4q+3) at ((q ^ (h&15))*8)          [16-start XOR: 2-way max]
// V path: 16 independent f4 vector loads/thread + in-register transpose
// (NO scalar column loads -- round-13's 117us bottleneck).
__global__ __launch_bounds__(256) void k_prep(
    const float* __restrict__ keys, const float* __restrict__ vals,
    unsigned short* __restrict__ kn, unsigned short* __restrict__ vbuf,
    int L, int CH, int TILES)
{
    const int bt = blockIdx.x;
    const int t = threadIdx.x;
    const int key0 = (bt / TILES) * CH + (bt % TILES) * 64;

    // ---- K part: 8 threads/row, 2 groups ----
    {
        const int r = t >> 3, j = t & 7;
        char* kdst = (char*)kn + (size_t)bt * 32768;
        #pragma unroll
        for (int grp = 0; grp < 2; ++grp) {
            int grow = key0 + grp * 32 + r;
            f4_t x[8];
            if (grow < L) {
                const float* src = keys + (size_t)grow * 256 + j * 32;
                #pragma unroll
                for (int k = 0; k < 8; ++k) x[k] = *(const f4_t*)(src + 4 * k);
            } else {
                #pragma unroll
                for (int k = 0; k < 8; ++k) x[k] = f4_t{0.f, 0.f, 0.f, 0.f};
            }
            float ss = 0.f;
            #pragma unroll
            for (int k = 0; k < 8; ++k)
                ss += x[k][0]*x[k][0] + x[k][1]*x[k][1]
                    + x[k][2]*x[k][2] + x[k][3]*x[k][3];
            ss += __shfl_xor(ss, 1, 64);
            ss += __shfl_xor(ss, 2, 64);
            ss += __shfl_xor(ss, 4, 64);
            float rn = 1.0f / fmaxf(sqrtf(ss), 1e-8f);
            char* gd = kdst + grp * 16384 + r * 512;
            #pragma unroll
            for (int k2 = 0; k2 < 4; ++k2) {
                us8_t uv;
                #pragma unroll
                for (int e = 0; e < 4; ++e) {
                    uv[e]     = fbf(x[2*k2][e]     * rn);
                    uv[e + 4] = fbf(x[2*k2 + 1][e] * rn);
                }
                *(us8_t*)(gd + ((j * 64 + k2 * 16) ^ (r * 16))) = uv;
            }
        }
    }
    // ---- V part: thread covers keys kb..kb+15 x h columns h0..h0+3 ----
    {
        const int kb = (t & 3) * 16;
        const int h0 = (t >> 2) * 4;
        f4_t r[16];
        #pragma unroll
        for (int i = 0; i < 16; ++i) {
            int row = key0 + kb + i;
            if (row >= L) row = L - 1;   // clamp; k_dnd masks p=0 for OOB keys
            r[i] = *(const f4_t*)&vals[(size_t)row * 256 + h0];
        }
        char* vdst = (char*)vbuf + (size_t)bt * 32768;
        #pragma unroll
        for (int j = 0; j < 4; ++j) {
            int hh = h0 + j;
            int x15 = hh & 15;
            char* vrow = vdst + hh * 128;
            #pragma unroll
            for (int s = 0; s < 4; ++s) {
                int q = (kb >> 2) + s;           // 8B slot = 4 keys
                union { uint32_t u[2]; us4_t v; } pv;
                pv.u[0] = cvtpk(r[4*s + 0][j], r[4*s + 1][j]);
                pv.u[1] = cvtpk(r[4*s + 2][j], r[4*s + 3][j]);
                *(us4_t*)(vrow + ((q ^ x15) * 8)) = pv.v;
            }
        }
    }
}

// ---------------- kernel 2: DND partials — pure gload_lds MFMA pipeline -----
// 224 blocks (1/CU), 512 threads = 8 waves; wave w owns b = w*32..+31 x 256 h.
// 64-key tiles; K (32KB) + V (32KB) double-buffered = 128KB LDS. Per tile per
// wave: 8 gload_lds (4 K + 4 V) -> counted vmcnt(8) -> barrier. ZERO inline
// conversion. GEMM1 swapped mfma32 (S[l][b], lane=b) + in-register softmax
// (T12 cvt_pk + permlane32_swap, split in halves for low reg pressure) +
// GEMM2. Each kn/vb byte fetched once.
__global__ __launch_bounds__(512, 2) void k_dnd(
    const unsigned short* __restrict__ kn, const unsigned short* __restrict__ vbuf,
    const unsigned short* __restrict__ qn,
    unsigned short* __restrict__ opart, float* __restrict__ dpart,
    int L, int CH, int TILES)
{
    // Kbuf0 @0 | Kbuf1 @32768 | Vbuf0 @65536 | Vbuf1 @98304   (128KB)
    __shared__ __align__(16) char smem[131072];

    const int t = threadIdx.x;
    const int w = t >> 6, lane = t & 63;
    const int l31 = lane & 31, hi = lane >> 5;

    const int chunk = blockIdx.x;
    const int base = chunk * CH;
    int nk = L - base;
    if (nk > CH) nk = CH;
    if (nk < 0) nk = 0;
    const int nt = (nk + 63) >> 6;

    // Q fragments: B-operand of swapped GEMM1 (col b = w*32 + l31)
    bf8_t qf[16];
    #pragma unroll
    for (int st = 0; st < 16; ++st)
        qf[st] = *(const bf8_t*)&qn[(w * 32 + l31) * 256 + st * 16 + hi * 8];
    asm volatile("s_waitcnt vmcnt(0)" ::: "memory");   // qf resolved; vmcnt
                                                       // now counts only DMAs
    f16_t o[8] = {};
    float den = 0.f;

    auto issue = [&](int tt) {
        size_t goff = (size_t)(chunk * TILES + tt) * 32768 + w * 4096;
        const char* ks = (const char*)kn + goff + lane * 16;
        const char* vs = (const char*)vbuf + goff + lane * 16;
        char* kd = smem + (tt & 1) * 32768 + w * 4096;
        char* vd = smem + 65536 + (tt & 1) * 32768 + w * 4096;
        #pragma unroll
        for (int c = 0; c < 4; ++c) gload_lds16(ks + c * 1024, kd + c * 1024);
        #pragma unroll
        for (int c = 0; c < 4; ++c) gload_lds16(vs + c * 1024, vd + c * 1024);
    };

    if (nt > 0) {
        issue(0);
        if (nt > 1) {
            issue(1);
            asm volatile("s_waitcnt vmcnt(8)" ::: "memory");
        } else {
            asm volatile("s_waitcnt vmcnt(0)" ::: "memory");
        }
        asm volatile("s_barrier" ::: "memory");

        for (int tt = 0; tt < nt; ++tt) {
            const char* Kb = smem + (tt & 1) * 32768;
            const char* Vb = smem + 65536 + (tt & 1) * 32768;

            #pragma unroll
            for (int u = 0; u < 2; ++u) {
                // ---- GEMM1 (swapped): S[l][b] = K @ Q^T, 16 d-steps ----
                f16_t sc = {};
                __builtin_amdgcn_s_setprio(1);
                #pragma unroll
                for (int st = 0; st < 16; ++st) {
                    bf8_t kf = *(const bf8_t*)(Kb + u * 16384 + l31 * 512 +
                                   (((2 * st + hi) * 16) ^ (l31 * 16)));
                    sc = mfma32(kf, qf[st], sc);
                }
                __builtin_amdgcn_s_setprio(0);

                // ---- in-register softmax, packed in 2 halves (low liveness) ----
                int kbase = tt * 64 + u * 32;
                bool full = (kbase + 32 <= nk);
                float ph[8];
                #pragma unroll
                for (int r = 0; r < 8; ++r) {
                    int l = (r & 3) + 8 * (r >> 2) + 4 * hi;
                    float pv = __expf(sc[r] - 1.0f);
                    if (!full && (kbase + l) >= nk) pv = 0.f;
                    ph[r] = pv;
                    den += pv;
                }
                uint32_t a0 = cvtpk(ph[0], ph[1]), a1 = cvtpk(ph[2], ph[3]);
                uint32_t b0 = cvtpk(ph[4], ph[5]), b1 = cvtpk(ph[6], ph[7]);
                asm("v_permlane32_swap_b32 %0, %1" : "+v"(a0), "+v"(b0));
                asm("v_permlane32_swap_b32 %0, %1" : "+v"(a1), "+v"(b1));
                union { uint32_t u4[4]; bf8_t v; } pa0, pa1;
                pa0.u4[0] = a0; pa0.u4[1] = a1; pa0.u4[2] = b0; pa0.u4[3] = b1;
                #pragma unroll
                for (int r = 8; r < 16; ++r) {
                    int l = (r & 3) + 8 * (r >> 2) + 4 * hi;
                    float pv = __expf(sc[r] - 1.0f);
                    if (!full && (kbase + l) >= nk) pv = 0.f;
                    ph[r - 8] = pv;
                    den += pv;
                }
                uint32_t c0 = cvtpk(ph[0], ph[1]), c1 = cvtpk(ph[2], ph[3]);
                uint32_t d0 = cvtpk(ph[4], ph[5]), d1 = cvtpk(ph[6], ph[7]);
                asm("v_permlane32_swap_b32 %0, %1" : "+v"(c0), "+v"(d0));
                asm("v_permlane32_swap_b32 %0, %1" : "+v"(c1), "+v"(d1));
                pa1.u4[0] = c0; pa1.u4[1] = c1; pa1.u4[2] = d0; pa1.u4[3] = d1;

                // ---- GEMM2: O[b][h] += P @ V (8 h-groups x 2 k-slices) ----
                __builtin_amdgcn_s_setprio(1);
                #pragma unroll
                for (int g = 0; g < 8; ++g) {
                    int hh = g * 32 + l31;
                    const char* vr = Vb + hh * 128;
                    int x15 = hh & 15;
                    int s0 = 8 * u + 2 * hi;
                    union { us4_t h4[2]; bf8_t v; } vf0, vf1;
                    vf0.h4[0] = *(const us4_t*)(vr + (((s0 + 0) ^ x15) * 8));
                    vf0.h4[1] = *(const us4_t*)(vr + (((s0 + 1) ^ x15) * 8));
                    vf1.h4[0] = *(const us4_t*)(vr + (((s0 + 4) ^ x15) * 8));
                    vf1.h4[1] = *(const us4_t*)(vr + (((s0 + 5) ^ x15) * 8));
                    o[g] = mfma32(pa0.v, vf0.v, o[g]);
                    o[g] = mfma32(pa1.v, vf1.v, o[g]);
                }
                __builtin_amdgcn_s_setprio(0);
            }

            // ---- sync: free buf[tt&1], prefetch t+2, ensure t+1 landed ----
            asm volatile("s_waitcnt lgkmcnt(0)\n\ts_barrier" ::: "memory");
            if (tt + 2 < nt) {
                issue(tt + 2);
                asm volatile("s_waitcnt vmcnt(8)" ::: "memory");
            } else {
                asm volatile("s_waitcnt vmcnt(0)" ::: "memory");
            }
            asm volatile("s_barrier" ::: "memory");
        }
    }

    // ---- epilogue: LDS transpose -> coalesced stores; den combine ----
    asm volatile("s_waitcnt vmcnt(0)" ::: "memory");
    __syncthreads();
    unsigned short* Ol = (unsigned short*)smem;   // [256 b][256 h] = 128KB
    #pragma unroll
    for (int g = 0; g < 8; ++g)
        #pragma unroll
        for (int r = 0; r < 16; ++r) {
            int b = w * 32 + (r & 3) + 8 * (r >> 2) + 4 * hi;
            Ol[b * 256 + g * 32 + l31] = fbf(o[g][r]);
        }
    __syncthreads();
    {
        size_t ob = (size_t)chunk * 65536;
        #pragma unroll
        for (int it = 0; it < 16; ++it) {
            int off = it * 4096 + t * 8;
            *(us8_t*)&opart[ob + off] = *(const us8_t*)&Ol[off];
        }
    }
    den += __shfl_xor(den, 32, 64);
    if (hi == 0)
        dpart[chunk * 256 + w * 32 + l31] = den;
}

// ---------------- kernel 3: reduce partials + LSTM epilogue -----------------
__global__ __launch_bounds__(256) void k_reduce(
    const unsigned short* __restrict__ opart, const float* __restrict__ dpart,
    const float* __restrict__ pre, const float* __restrict__ c_in,
    float* __restrict__ out)
{
    __shared__ float sred[4];
    int b = blockIdx.x, t = threadIdx.x;

    float ds = (t < NCH) ? dpart[t * 256 + b] : 0.0f;
    #pragma unroll
    for (int m = 1; m < 64; m <<= 1) ds += __shfl_xor(ds, m, 64);
    if ((t & 63) == 0) sred[t >> 6] = ds;
    __syncthreads();
    float dtot = fmaxf(sred[0] + sred[1] + sred[2] + sred[3], 1e-30f);

    size_t sb = (size_t)b * 256 + t;
    float n0 = 0.f, n1 = 0.f, n2 = 0.f, n3 = 0.f;
    for (int ck = 0; ck < NCH; ck += 4) {
        n0 += bf2f(opart[(size_t)(ck + 0) * 65536 + sb]);
        n1 += bf2f(opart[(size_t)(ck + 1) * 65536 + sb]);
        n2 += bf2f(opart[(size_t)(ck + 2) * 65536 + sb]);
        n3 += bf2f(opart[(size_t)(ck + 3) * 65536 + sb]);
    }
    float num = (n0 + n1) + (n2 + n3);

    float m = tanhf(num / dtot);
    const float* p = pre + b * 1280;
    float fg = sigf(p[t]);
    float ig = sigf(p[256 + t]);
    float og = sigf(p[512 + t]);
    float rg = sigf(p[768 + t]);
    float cn = tanhf(p[1024 + t]);
    float co = c_in[b * 256 + t];
    float ct = fg * co + ig * cn + rg * m;
    float ht = og * tanhf(ct);
    out[b * 256 + t] = ht;
    out[65536 + b * 256 + t] = ct;
}

// ---------------- launch ----------------------------------------------------
extern "C" void kernel_launch(void* const* d_in, const int* in_sizes, int n_in,
                              void* d_out, int out_size, void* d_ws, size_t ws_size,
                              hipStream_t stream)
{
    const float* x    = (const float*)d_in[0];
    const float* h    = (const float*)d_in[1];
    const float* c    = (const float*)d_in[2];
    const float* W1   = (const float*)d_in[3];
    const float* b1   = (const float*)d_in[4];
    const float* W2   = (const float*)d_in[5];
    const float* b2   = (const float*)d_in[6];
    const float* keys = (const float*)d_in[7];
    const float* vals = (const float*)d_in[8];
    int L = in_sizes[7] / 256;

    // NCH chunks, each TILES tiles of 64 keys
    int TILES = (L + NCH * 64 - 1) / (NCH * 64);      // 7 for L=100000
    int CH = TILES * 64;                              // 448
    int NT = NCH * TILES;                             // total tiles = 1568

    char* ws = (char*)d_ws;
    unsigned short* qn    = (unsigned short*)(ws + 0);
    unsigned short* xb    = (unsigned short*)(ws + 131072);
    unsigned short* hb    = (unsigned short*)(ws + 262144);
    unsigned short* w1b   = (unsigned short*)(ws + 393216);
    unsigned short* w2b   = (unsigned short*)(ws + 1048576);
    float*          pre   = (float*)(ws + 1703936);
    float*          dpart = (float*)(ws + 3014656);              // NCH*256 f32
    unsigned short* kn    = (unsigned short*)(ws + 3276800);
    unsigned short* vb    = (unsigned short*)(ws + 3276800 + (size_t)NT * 32768);
    unsigned short* opart = (unsigned short*)(ws + 3276800 + (size_t)NT * 65536);

    k_convert<<<dim3(1024), dim3(256), 0, stream>>>(x, h, W1, W2, qn, xb, hb, w1b, w2b);
    k_gates<<<dim3(80), dim3(256), 0, stream>>>(xb, hb, w1b, w2b, b1, b2, pre);
    k_prep<<<dim3(NT), dim3(256), 0, stream>>>(keys, vals, kn, vb, L, CH, TILES);
    k_dnd<<<dim3(NCH), dim3(512), 0, stream>>>(kn, vb, qn, opart, dpart, L, CH, TILES);
    k_reduce<<<dim3(256), dim3(256), 0, stream>>>(opart, dpart, pre, c, (float*)d_out);

    (void)n_in; (void)out_size; (void)ws_size;
}